// Round 3
// baseline (928.232 us; speedup 1.0000x reference)
//
#include <hip/hip_runtime.h>

// Masked cumsum along dim=1, x:(256,131072) f32, mask int32, out f32.
//
// Single-pass decoupled-lookback scan (rocPRIM/CUB style):
//   - 4096 blocks: 256 rows x 16 partitions of 8192 elements.
//   - Each block grabs a ticket (atomicAdd) for its virtual id. Predecessor
//     partitions have lower tickets => were grabbed by already-started blocks
//     => GPU workgroups run to completion => lookback spin always terminates.
//   - Per-partition descriptor: uint64 = (flag<<32)|float_bits in d_ws.
//     flag: 0=invalid (memset 0), 1=aggregate, 2=inclusive prefix.
//     Partition 0 publishes flag=2 directly, so once all 15 predecessors are
//     non-invalid the window ALWAYS contains a prefix -> one-shot lookback.
//   - Data loaded once into registers (4x float4 + 4x int4 per thread),
//     thread scan(16) -> wave shfl scan -> block combine -> +prefix -> store.
// Traffic: 256 MiB read + 128 MiB write + ~64 KiB flags; floor ~43-61 us.

#define N_ROWS   256
#define N_COLS   131072
#define BLOCK    512
#define VPT      16
#define NV4      (VPT / 4)
#define PART     (BLOCK * VPT)       // 8192 elements per partition
#define PPR      (N_COLS / PART)     // 16 partitions per row
#define NBLOCKS  (N_ROWS * PPR)      // 4096
#define NWAVES   (BLOCK / 64)        // 8

#define WS_TICKET_OFF 0
#define WS_FLAGS_OFF  64
#define WS_BYTES      (WS_FLAGS_OFF + NBLOCKS * 8)

__device__ __forceinline__ unsigned long long pack_desc(unsigned long long flag, float v) {
    union { float f; unsigned u; } c; c.f = v;
    return (flag << 32) | (unsigned long long)c.u;
}

__global__ __launch_bounds__(BLOCK)
void masked_cumsum_lookback(const float* __restrict__ x,
                            const int* __restrict__ mask,
                            float* __restrict__ out,
                            unsigned int* __restrict__ ticket,
                            unsigned long long* __restrict__ flags) {
    __shared__ float waveSums[NWAVES];
    __shared__ float s_excl;
    __shared__ unsigned int s_vid;

    const int tid  = threadIdx.x;
    const int lane = tid & 63;
    const int wave = tid >> 6;

    if (tid == 0) s_vid = atomicAdd(ticket, 1u);
    __syncthreads();
    const unsigned vid = s_vid;
    const int row  = (int)(vid >> 4);        // vid / PPR
    const int part = (int)(vid & (PPR - 1)); // vid % PPR

    const size_t gbase = (size_t)row * N_COLS + (size_t)part * PART;
    const float4* __restrict__ x4 = (const float4*)(x + gbase);
    const int4*   __restrict__ m4 = (const int4*)(mask + gbase);
    float4*       __restrict__ o4 = (float4*)(out + gbase);

    // Load this partition once (blocked: thread owns 16 contiguous elems).
    float4 xa[NV4];
    int4   ma[NV4];
    #pragma unroll
    for (int k = 0; k < NV4; ++k) {
        xa[k] = x4[tid * NV4 + k];
        ma[k] = m4[tid * NV4 + k];
    }

    // Thread-local inclusive scan of 16 masked values.
    float s[VPT];
    float run = 0.0f;
    #pragma unroll
    for (int k = 0; k < NV4; ++k) {
        run += ma[k].x ? xa[k].x : 0.0f; s[4*k+0] = run;
        run += ma[k].y ? xa[k].y : 0.0f; s[4*k+1] = run;
        run += ma[k].z ? xa[k].z : 0.0f; s[4*k+2] = run;
        run += ma[k].w ? xa[k].w : 0.0f; s[4*k+3] = run;
    }
    const float tsum = run;

    // Wave-level inclusive scan over 64 lanes.
    float incl = tsum;
    #pragma unroll
    for (int d = 1; d < 64; d <<= 1) {
        const float y = __shfl_up(incl, d, 64);
        if (lane >= d) incl += y;
    }
    const float waveExcl = incl - tsum;

    if (lane == 63) waveSums[wave] = incl;
    __syncthreads();

    float waveOff = 0.0f, blockTot = 0.0f;
    #pragma unroll
    for (int w = 0; w < NWAVES; ++w) {
        const float v = waveSums[w];
        if (w < wave) waveOff += v;
        blockTot += v;
    }

    // Wave 0: publish descriptor + lookback.
    if (wave == 0) {
        if (part == 0) {
            if (lane == 0) {
                __hip_atomic_store(&flags[vid], pack_desc(2ull, blockTot),
                                   __ATOMIC_RELEASE, __HIP_MEMORY_SCOPE_AGENT);
                s_excl = 0.0f;
            }
        } else {
            if (lane == 0) {
                __hip_atomic_store(&flags[vid], pack_desc(1ull, blockTot),
                                   __ATOMIC_RELEASE, __HIP_MEMORY_SCOPE_AGENT);
            }
            // Parallel lookback: lane i watches predecessor (part-1-i).
            const unsigned long long* fr = flags + ((size_t)row << 4);
            float excl = 0.0f;
            for (;;) {
                int   flg = 2;     // lanes >= part: fake far-away prefix, val 0
                float val = 0.0f;
                if (lane < part) {
                    const unsigned long long e =
                        __hip_atomic_load(&fr[part - 1 - lane],
                                          __ATOMIC_ACQUIRE, __HIP_MEMORY_SCOPE_AGENT);
                    flg = (int)(e >> 32);
                    union { unsigned u; float f; } c;
                    c.u = (unsigned)(e & 0xffffffffu);
                    val = c.f;
                }
                if (__ballot(flg == 0) != 0ull) {
                    __builtin_amdgcn_s_sleep(1);
                    continue;  // some predecessor not yet published
                }
                // All valid. Partition 0 publishes flag=2, so a real prefix
                // exists at lane <= part-1; nearest = lowest set lane.
                const unsigned long long pfx = __ballot(flg == 2);
                const int istar = __ffsll((long long)pfx) - 1;
                // exclusive = prefix(istar) + sum of aggregates closer than it
                float c = (lane <= istar) ? val : 0.0f;
                #pragma unroll
                for (int m = 1; m < 64; m <<= 1) c += __shfl_xor(c, m, 64);
                excl = c;
                break;
            }
            if (lane == 0) {
                __hip_atomic_store(&flags[vid], pack_desc(2ull, excl + blockTot),
                                   __ATOMIC_RELEASE, __HIP_MEMORY_SCOPE_AGENT);
                s_excl = excl;
            }
        }
    }
    __syncthreads();

    const float basev = s_excl + waveOff + waveExcl;
    #pragma unroll
    for (int k = 0; k < NV4; ++k) {
        float4 r;
        r.x = basev + s[4*k+0];
        r.y = basev + s[4*k+1];
        r.z = basev + s[4*k+2];
        r.w = basev + s[4*k+3];
        o4[tid * NV4 + k] = r;
    }
}

extern "C" void kernel_launch(void* const* d_in, const int* in_sizes, int n_in,
                              void* d_out, int out_size, void* d_ws, size_t ws_size,
                              hipStream_t stream) {
    const float* x    = (const float*)d_in[0];
    const int*   mask = (const int*)d_in[1];
    float*       out  = (float*)d_out;
    (void)in_sizes; (void)n_in; (void)out_size; (void)ws_size;

    unsigned int* ticket = (unsigned int*)((char*)d_ws + WS_TICKET_OFF);
    unsigned long long* flags = (unsigned long long*)((char*)d_ws + WS_FLAGS_OFF);

    // d_ws is re-poisoned to 0xAA before every launch: zero ticket + flags.
    // Async memset on the stream is a legal graph-capture node.
    hipMemsetAsync(d_ws, 0, WS_BYTES, stream);

    masked_cumsum_lookback<<<NBLOCKS, BLOCK, 0, stream>>>(x, mask, out, ticket, flags);
}

// Round 4
// 330.993 us; speedup vs baseline: 2.8044x; 2.8044x over previous
//
#include <hip/hip_runtime.h>

// Masked cumsum along dim=1, x:(256,131072) f32, mask int32, out f32.
//
// Single-pass decoupled-lookback scan, round-3 fixes:
//  - RELAXED agent-scope atomics only. Flag+value share one 64-bit word, so
//    no acquire/release fences are needed; round 3's per-poll acquire
//    (cache-invalidate) and per-publish release (L2 writeback) storms
//    collapsed HBM to 530 GB/s.
//  - Live set across the spin cut to v[16] masked floats (round 3 spilled:
//    VGPR 24 + 118 MB scratch writes). Final scan is recomputed from v[]
//    after the prefix arrives.
//  - s_sleep(32) backoff (~0.85us) instead of s_sleep(1).
// Ticket-ordered virtual block ids keep the spin deadlock-free: all
// predecessors of ticket k were grabbed by blocks that already started and
// publish their aggregate without waiting on anyone.

#define N_ROWS   256
#define N_COLS   131072
#define BLOCK    512
#define VPT      16
#define NV4      (VPT / 4)
#define PART     (BLOCK * VPT)       // 8192 elements per partition
#define PPR      (N_COLS / PART)     // 16 partitions per row
#define NBLOCKS  (N_ROWS * PPR)      // 4096
#define NWAVES   (BLOCK / 64)        // 8

#define WS_TICKET_OFF 0
#define WS_FLAGS_OFF  64
#define WS_BYTES      (WS_FLAGS_OFF + NBLOCKS * 8)

__device__ __forceinline__ unsigned long long pack_desc(unsigned long long flag, float v) {
    union { float f; unsigned u; } c; c.f = v;
    return (flag << 32) | (unsigned long long)c.u;
}

__global__ __launch_bounds__(BLOCK)
void masked_cumsum_lookback(const float* __restrict__ x,
                            const int* __restrict__ mask,
                            float* __restrict__ out,
                            unsigned int* __restrict__ ticket,
                            unsigned long long* __restrict__ flags) {
    __shared__ float waveSums[NWAVES];
    __shared__ float s_excl;
    __shared__ unsigned int s_vid;

    const int tid  = threadIdx.x;
    const int lane = tid & 63;
    const int wave = tid >> 6;

    if (tid == 0) s_vid = atomicAdd(ticket, 1u);
    __syncthreads();
    const unsigned vid = s_vid;
    const int row  = (int)(vid >> 4);        // vid / PPR
    const int part = (int)(vid & (PPR - 1)); // vid % PPR

    const size_t gbase = (size_t)row * N_COLS + (size_t)part * PART;
    const float4* __restrict__ x4 = (const float4*)(x + gbase);
    const int4*   __restrict__ m4 = (const int4*)(mask + gbase);
    float4*       __restrict__ o4 = (float4*)(out + gbase);

    // Load once; keep ONLY the 16 masked floats live past this point.
    float v[VPT];
    #pragma unroll
    for (int k = 0; k < NV4; ++k) {
        const float4 cx = x4[tid * NV4 + k];
        const int4   cm = m4[tid * NV4 + k];
        v[4*k+0] = cm.x ? cx.x : 0.0f;
        v[4*k+1] = cm.y ? cx.y : 0.0f;
        v[4*k+2] = cm.z ? cx.z : 0.0f;
        v[4*k+3] = cm.w ? cx.w : 0.0f;
    }
    float tsum = 0.0f;
    #pragma unroll
    for (int k = 0; k < VPT; ++k) tsum += v[k];

    // Wave-level inclusive scan of per-thread sums.
    float incl = tsum;
    #pragma unroll
    for (int d = 1; d < 64; d <<= 1) {
        const float y = __shfl_up(incl, d, 64);
        if (lane >= d) incl += y;
    }
    const float waveExcl = incl - tsum;

    if (lane == 63) waveSums[wave] = incl;
    __syncthreads();

    float waveOff = 0.0f, blockTot = 0.0f;
    #pragma unroll
    for (int w = 0; w < NWAVES; ++w) {
        const float s = waveSums[w];
        if (w < wave) waveOff += s;
        blockTot += s;
    }

    // Wave 0: publish + lookback. All atomics RELAXED (payload is in-word).
    if (wave == 0) {
        if (part == 0) {
            if (lane == 0) {
                __hip_atomic_store(&flags[vid], pack_desc(2ull, blockTot),
                                   __ATOMIC_RELAXED, __HIP_MEMORY_SCOPE_AGENT);
                s_excl = 0.0f;
            }
        } else {
            if (lane == 0) {
                __hip_atomic_store(&flags[vid], pack_desc(1ull, blockTot),
                                   __ATOMIC_RELAXED, __HIP_MEMORY_SCOPE_AGENT);
            }
            const unsigned long long* fr = flags + ((size_t)row << 4);
            float excl = 0.0f;
            for (;;) {
                int   flg = 2;     // lanes >= part: fake far prefix, val 0
                float val = 0.0f;
                if (lane < part) {
                    const unsigned long long e =
                        __hip_atomic_load(&fr[part - 1 - lane],
                                          __ATOMIC_RELAXED, __HIP_MEMORY_SCOPE_AGENT);
                    flg = (int)(e >> 32);
                    union { unsigned u; float f; } c;
                    c.u = (unsigned)(e & 0xffffffffu);
                    val = c.f;
                }
                if (__ballot(flg == 0) != 0ull) {
                    __builtin_amdgcn_s_sleep(32);   // ~0.85us backoff
                    continue;
                }
                // All predecessors valid; partition 0 always has flag=2, so
                // the nearest prefix is the lowest set lane.
                const unsigned long long pfx = __ballot(flg == 2);
                const int istar = __ffsll((long long)pfx) - 1;
                float c = (lane <= istar) ? val : 0.0f;
                #pragma unroll
                for (int m = 1; m < 64; m <<= 1) c += __shfl_xor(c, m, 64);
                excl = c;
                break;
            }
            if (lane == 0) {
                __hip_atomic_store(&flags[vid], pack_desc(2ull, excl + blockTot),
                                   __ATOMIC_RELAXED, __HIP_MEMORY_SCOPE_AGENT);
                s_excl = excl;
            }
        }
    }
    __syncthreads();

    // Recompute the per-thread scan from v[] and store.
    float run = s_excl + waveOff + waveExcl;
    #pragma unroll
    for (int k = 0; k < NV4; ++k) {
        float4 r;
        run += v[4*k+0]; r.x = run;
        run += v[4*k+1]; r.y = run;
        run += v[4*k+2]; r.z = run;
        run += v[4*k+3]; r.w = run;
        o4[tid * NV4 + k] = r;
    }
}

extern "C" void kernel_launch(void* const* d_in, const int* in_sizes, int n_in,
                              void* d_out, int out_size, void* d_ws, size_t ws_size,
                              hipStream_t stream) {
    const float* x    = (const float*)d_in[0];
    const int*   mask = (const int*)d_in[1];
    float*       out  = (float*)d_out;
    (void)in_sizes; (void)n_in; (void)out_size; (void)ws_size;

    unsigned int* ticket = (unsigned int*)((char*)d_ws + WS_TICKET_OFF);
    unsigned long long* flags = (unsigned long long*)((char*)d_ws + WS_FLAGS_OFF);

    hipMemsetAsync(d_ws, 0, WS_BYTES, stream);
    masked_cumsum_lookback<<<NBLOCKS, BLOCK, 0, stream>>>(x, mask, out, ticket, flags);
}